// Round 1
// baseline (179.715 us; speedup 1.0000x reference)
//
#include <hip/hip_runtime.h>

#define NN   2500
#define NE   10000
#define EMBD 32
#define NH   4
#define DHD  8
#define FFD  32
#define EPSC 1e-5f

__device__ __forceinline__ float dot4(float4 a, float4 b) {
    return a.x * b.x + a.y * b.y + a.z * b.z + a.w * b.w;
}

// One FFN path for one (edge, head), executed by one 64-lane wave.
// lane = f2*2 + half; lane covers layer-1 weight row f2, columns [half*16, half*16+16).
// Returns the LayerNorm'd DH-output: 4 floats per lane for k = half*4 + j.
__device__ __forceinline__ float4 ffn_path(
    const float4* fs, const float4* fd,
    const float* __restrict__ uw, const float* __restrict__ vw,
    const float* __restrict__ ub, const float* __restrict__ vb,
    const float* __restrict__ ew, const float* __restrict__ eb,
    const float* __restrict__ gam, const float* __restrict__ bet,
    int lane, int f2, int half)
{
    const float4* u4 = (const float4*)(uw + lane * 16);
    const float4* v4 = (const float4*)(vw + lane * 16);
    float p = dot4(u4[0], fs[0]) + dot4(u4[1], fs[1])
            + dot4(u4[2], fs[2]) + dot4(u4[3], fs[3])
            + dot4(v4[0], fd[0]) + dot4(v4[1], fd[1])
            + dot4(v4[2], fd[2]) + dot4(v4[3], fd[3]);
    p += __shfl_xor(p, 1);                     // complete EMB=32 dot across the pair
    float hv = fmaxf(p + ub[f2] + vb[f2], 0.0f);

    // layer 2: o[k] = sum_f ew[f][k] * h[f]; lane holds k = half*4 .. half*4+3
    float4 w2 = *(const float4*)(ew + f2 * DHD + half * 4);
    float4 o;
    o.x = w2.x * hv; o.y = w2.y * hv; o.z = w2.z * hv; o.w = w2.w * hv;
    #pragma unroll
    for (int m = 2; m <= 32; m <<= 1) {        // reduce over the 32 f-rows
        o.x += __shfl_xor(o.x, m);
        o.y += __shfl_xor(o.y, m);
        o.z += __shfl_xor(o.z, m);
        o.w += __shfl_xor(o.w, m);
    }
    float4 b2 = *(const float4*)(eb + half * 4);
    o.x += b2.x; o.y += b2.y; o.z += b2.z; o.w += b2.w;

    // LayerNorm over DH=8 (4 local + 4 in the paired lane)
    float s1 = o.x + o.y + o.z + o.w;
    float s2 = o.x * o.x + o.y * o.y + o.z * o.z + o.w * o.w;
    s1 += __shfl_xor(s1, 1);
    s2 += __shfl_xor(s2, 1);
    float mean = s1 * 0.125f;
    float var  = s2 * 0.125f - mean * mean;
    float rs   = rsqrtf(var + EPSC);
    float4 g4  = *(const float4*)(gam + half * 4);
    float4 bt4 = *(const float4*)(bet + half * 4);
    o.x = (o.x - mean) * rs * g4.x + bt4.x;
    o.y = (o.y - mean) * rs * g4.y + bt4.y;
    o.z = (o.z - mean) * rs * g4.z + bt4.z;
    o.w = (o.w - mean) * rs * g4.w + bt4.w;
    return o;
}

__global__ __launch_bounds__(256) void edge_kernel(
    const float* __restrict__ feat, const float* __restrict__ query,
    const float* __restrict__ skw, const float* __restrict__ dkw,
    const float* __restrict__ skb, const float* __restrict__ dkb,
    const float* __restrict__ ekw, const float* __restrict__ ekb,
    const float* __restrict__ svw, const float* __restrict__ dvw,
    const float* __restrict__ svb, const float* __restrict__ dvb,
    const float* __restrict__ evw, const float* __restrict__ evb,
    const float* __restrict__ kg, const float* __restrict__ kbeta,
    const float* __restrict__ vg, const float* __restrict__ vbeta,
    const int* __restrict__ src, const int* __restrict__ dst,
    float* __restrict__ s_den, float* __restrict__ ex_out,
    float* __restrict__ v_out)
{
    int gid = blockIdx.x * 256 + threadIdx.x;
    int wid = gid >> 6;                 // one wave per (edge, head)
    if (wid >= NE * NH) return;
    int lane = threadIdx.x & 63;
    int e    = wid >> 2;                // wid / NH
    int hh   = wid & 3;                 // wid % NH
    int half = lane & 1;
    int f2   = lane >> 1;
    int sn = src[e], dn = dst[e];

    // 16-float slices of source/dest node features (L2-resident, broadcast)
    const float4* fsp = (const float4*)(feat + sn * EMBD + half * 16);
    const float4* fdp = (const float4*)(feat + dn * EMBD + half * 16);
    float4 fsr[4], fdr[4];
    #pragma unroll
    for (int j = 0; j < 4; j++) { fsr[j] = fsp[j]; fdr[j] = fdp[j]; }

    int eh = wid;
    // ---- key path ----
    float4 kn = ffn_path(fsr, fdr,
                         skw + (size_t)eh * 1024, dkw + (size_t)eh * 1024,
                         skb + eh * 32, dkb + eh * 32,
                         ekw + eh * 256, ekb + eh * 8,
                         kg, kbeta, lane, f2, half);
    float4 q4 = *(const float4*)(query + eh * 8 + half * 4);
    float lp = dot4(kn, q4);
    lp += __shfl_xor(lp, 1);            // full DH=8 dot

    // ---- value path ----
    float4 vn = ffn_path(fsr, fdr,
                         svw + (size_t)eh * 1024, dvw + (size_t)eh * 1024,
                         svb + eh * 32, dvb + eh * 32,
                         evw + eh * 256, evb + eh * 8,
                         vg, vbeta, lane, f2, half);

    if (lane < 2)
        *(float4*)(v_out + eh * 8 + half * 4) = vn;
    if (lane == 0) {
        float exv = expf(lp);           // no max-subtraction: identical softmax
        ex_out[eh] = exv;
        atomicAdd(s_den + dn * NH + hh, exv);
    }
}

__global__ void zero_kernel(float* __restrict__ p, int n) {
    int i = blockIdx.x * blockDim.x + threadIdx.x;
    if (i < n) p[i] = 0.0f;
}

__global__ void attn_agg_kernel(
    const int* __restrict__ dst, const float* __restrict__ ex,
    const float* __restrict__ s_den, const float* __restrict__ v,
    float* __restrict__ agg, float* __restrict__ attn_out)
{
    int tid = blockIdx.x * blockDim.x + threadIdx.x;
    if (tid >= NE * NH * DHD) return;
    int eh = tid >> 3;
    int dd = tid & 7;
    int e  = eh >> 2;
    int h  = eh & 3;
    int dn = dst[e];
    float a = ex[eh] / s_den[dn * NH + h];
    if (dd == 0) attn_out[eh] = a;
    atomicAdd(agg + (dn * NH + h) * DHD + dd, v[tid] * a);
}

__global__ void out_ln_kernel(
    const float* __restrict__ agg, const float* __restrict__ g,
    const float* __restrict__ b, float* __restrict__ out)
{
    int tid = blockIdx.x * blockDim.x + threadIdx.x;
    if (tid >= NN * NH) return;
    float4 a0 = *(const float4*)(agg + tid * 8);
    float4 a1 = *(const float4*)(agg + tid * 8 + 4);
    float s1 = a0.x + a0.y + a0.z + a0.w + a1.x + a1.y + a1.z + a1.w;
    float s2 = a0.x * a0.x + a0.y * a0.y + a0.z * a0.z + a0.w * a0.w
             + a1.x * a1.x + a1.y * a1.y + a1.z * a1.z + a1.w * a1.w;
    float mean = s1 * 0.125f;
    float var  = s2 * 0.125f - mean * mean;
    float rs   = rsqrtf(var + EPSC);
    float4 g0 = *(const float4*)(g);
    float4 g1 = *(const float4*)(g + 4);
    float4 b0 = *(const float4*)(b);
    float4 b1 = *(const float4*)(b + 4);
    float4 r0, r1;
    r0.x = (a0.x - mean) * rs * g0.x + b0.x;
    r0.y = (a0.y - mean) * rs * g0.y + b0.y;
    r0.z = (a0.z - mean) * rs * g0.z + b0.z;
    r0.w = (a0.w - mean) * rs * g0.w + b0.w;
    r1.x = (a1.x - mean) * rs * g1.x + b1.x;
    r1.y = (a1.y - mean) * rs * g1.y + b1.y;
    r1.z = (a1.z - mean) * rs * g1.z + b1.z;
    r1.w = (a1.w - mean) * rs * g1.w + b1.w;
    *(float4*)(out + tid * 8)     = r0;
    *(float4*)(out + tid * 8 + 4) = r1;
}

extern "C" void kernel_launch(void* const* d_in, const int* in_sizes, int n_in,
                              void* d_out, int out_size, void* d_ws, size_t ws_size,
                              hipStream_t stream) {
    const float* feat  = (const float*)d_in[0];
    const float* query = (const float*)d_in[1];
    const float* skw   = (const float*)d_in[2];
    const float* dkw   = (const float*)d_in[3];
    const float* skb   = (const float*)d_in[4];
    const float* dkb   = (const float*)d_in[5];
    const float* ekw   = (const float*)d_in[6];
    const float* ekb   = (const float*)d_in[7];
    const float* svw   = (const float*)d_in[8];
    const float* dvw   = (const float*)d_in[9];
    const float* svb   = (const float*)d_in[10];
    const float* dvb   = (const float*)d_in[11];
    const float* evw   = (const float*)d_in[12];
    const float* evb   = (const float*)d_in[13];
    const float* kg    = (const float*)d_in[14];
    const float* kbeta = (const float*)d_in[15];
    const float* vg    = (const float*)d_in[16];
    const float* vbeta = (const float*)d_in[17];
    const float* og    = (const float*)d_in[18];
    const float* obeta = (const float*)d_in[19];
    const int*   src   = (const int*)d_in[20];
    const int*   dst   = (const int*)d_in[21];
    // d_in[22] = i, always 0 (L=1)

    float* ws    = (float*)d_ws;
    float* s_den = ws;                 // N*H          = 10000
    float* agg   = ws + 10000;         // N*H*DH       = 80000
    float* ex    = ws + 90000;         // E*H          = 40000
    float* vbuf  = ws + 130000;        // E*H*DH       = 320000

    float* out  = (float*)d_out;       // N*EMB = 80000 floats
    float* attn = out + NN * EMBD;     // E*H   = 40000 floats

    zero_kernel<<<(90000 + 255) / 256, 256, 0, stream>>>(ws, 90000);

    edge_kernel<<<(NE * NH * 64) / 256, 256, 0, stream>>>(
        feat, query, skw, dkw, skb, dkb, ekw, ekb,
        svw, dvw, svb, dvb, evw, evb,
        kg, kbeta, vg, vbeta, src, dst,
        s_den, ex, vbuf);

    attn_agg_kernel<<<(NE * NH * DHD + 255) / 256, 256, 0, stream>>>(
        dst, ex, s_den, vbuf, agg, attn);

    out_ln_kernel<<<(NN * NH + 255) / 256, 256, 0, stream>>>(
        agg, og, obeta, out);
}

// Round 2
// 167.195 us; speedup vs baseline: 1.0749x; 1.0749x over previous
//
#include <hip/hip_runtime.h>

#define NN   2500
#define NE   10000
#define EMBD 32
#define NH   4
#define DHD  8
#define FFD  32
#define EPSC 1e-5f

__device__ __forceinline__ float dot4(float4 a, float4 b) {
    return a.x * b.x + a.y * b.y + a.z * b.z + a.w * b.w;
}

// Compute one FFN path from PRE-LOADED registers.
// lane = f2*2 + half; layer-1 row f2, cols [half*16, half*16+16).
// u[4]/v[4]: layer-1 weight slices. w2: layer-2 row chunk ew[f2][half*4..+4].
// b1 = ub[f2]+vb[f2]. b2 = eb[half*4..+4]. Returns LN'd outputs k=half*4..+4.
__device__ __forceinline__ float4 ffn_compute(
    const float4* fs, const float4* fd,
    const float4* u, const float4* v,
    float4 w2, float b1, float4 b2,
    float4 g4, float4 bt4)
{
    float p = dot4(u[0], fs[0]) + dot4(u[1], fs[1])
            + dot4(u[2], fs[2]) + dot4(u[3], fs[3])
            + dot4(v[0], fd[0]) + dot4(v[1], fd[1])
            + dot4(v[2], fd[2]) + dot4(v[3], fd[3]);
    p += __shfl_xor(p, 1);                     // complete EMB=32 dot
    float hv = fmaxf(p + b1, 0.0f);

    float4 o;
    o.x = w2.x * hv; o.y = w2.y * hv; o.z = w2.z * hv; o.w = w2.w * hv;
    #pragma unroll
    for (int m = 2; m <= 32; m <<= 1) {        // reduce over 32 f-rows
        o.x += __shfl_xor(o.x, m);
        o.y += __shfl_xor(o.y, m);
        o.z += __shfl_xor(o.z, m);
        o.w += __shfl_xor(o.w, m);
    }
    o.x += b2.x; o.y += b2.y; o.z += b2.z; o.w += b2.w;

    // LayerNorm over DH=8 (4 local + 4 in paired lane)
    float s1 = o.x + o.y + o.z + o.w;
    float s2 = o.x * o.x + o.y * o.y + o.z * o.z + o.w * o.w;
    s1 += __shfl_xor(s1, 1);
    s2 += __shfl_xor(s2, 1);
    float mean = s1 * 0.125f;
    float var  = s2 * 0.125f - mean * mean;
    float rs   = rsqrtf(var + EPSC);
    o.x = (o.x - mean) * rs * g4.x + bt4.x;
    o.y = (o.y - mean) * rs * g4.y + bt4.y;
    o.z = (o.z - mean) * rs * g4.z + bt4.z;
    o.w = (o.w - mean) * rs * g4.w + bt4.w;
    return o;
}

__global__ __launch_bounds__(256) void edge_kernel(
    const float* __restrict__ feat, const float* __restrict__ query,
    const float* __restrict__ skw, const float* __restrict__ dkw,
    const float* __restrict__ skb, const float* __restrict__ dkb,
    const float* __restrict__ ekw, const float* __restrict__ ekb,
    const float* __restrict__ svw, const float* __restrict__ dvw,
    const float* __restrict__ svb, const float* __restrict__ dvb,
    const float* __restrict__ evw, const float* __restrict__ evb,
    const float* __restrict__ kg, const float* __restrict__ kbeta,
    const float* __restrict__ vg, const float* __restrict__ vbeta,
    const int* __restrict__ src, const int* __restrict__ dst,
    float* __restrict__ s_den, float* __restrict__ ex_out,
    float* __restrict__ v_out)
{
    int gid = blockIdx.x * 256 + threadIdx.x;
    int wid = gid >> 6;                 // one wave per (edge, head)
    if (wid >= NE * NH) return;
    int lane = threadIdx.x & 63;
    int e    = wid >> 2;
    int hh   = wid & 3;
    int half = lane & 1;
    int f2   = lane >> 1;
    int sn = src[e], dn = dst[e];
    size_t eh = (size_t)wid;

    // ---------- issue ALL loads up front (max memory-level parallelism) ----
    const float4* ku_p = (const float4*)(skw + eh * 1024 + lane * 16);
    const float4* kv_p = (const float4*)(dkw + eh * 1024 + lane * 16);
    const float4* vu_p = (const float4*)(svw + eh * 1024 + lane * 16);
    const float4* vv_p = (const float4*)(dvw + eh * 1024 + lane * 16);

    float4 ku[4], kv[4], vu[4], vv[4];
    #pragma unroll
    for (int j = 0; j < 4; j++) ku[j] = ku_p[j];
    #pragma unroll
    for (int j = 0; j < 4; j++) kv[j] = kv_p[j];
    #pragma unroll
    for (int j = 0; j < 4; j++) vu[j] = vu_p[j];
    #pragma unroll
    for (int j = 0; j < 4; j++) vv[j] = vv_p[j];

    float4 kw2 = *(const float4*)(ekw + eh * 256 + f2 * DHD + half * 4);
    float4 vw2 = *(const float4*)(evw + eh * 256 + f2 * DHD + half * 4);
    float  kb1 = skb[eh * 32 + f2] + dkb[eh * 32 + f2];
    float  vb1 = svb[eh * 32 + f2] + dvb[eh * 32 + f2];
    float4 kb2 = *(const float4*)(ekb + eh * 8 + half * 4);
    float4 vb2 = *(const float4*)(evb + eh * 8 + half * 4);
    float4 q4  = *(const float4*)(query + eh * 8 + half * 4);

    const float4* fsp = (const float4*)(feat + sn * EMBD + half * 16);
    const float4* fdp = (const float4*)(feat + dn * EMBD + half * 16);
    float4 fsr[4], fdr[4];
    #pragma unroll
    for (int j = 0; j < 4; j++) { fsr[j] = fsp[j]; fdr[j] = fdp[j]; }

    float4 kgam = *(const float4*)(kg    + half * 4);
    float4 kbet = *(const float4*)(kbeta + half * 4);
    float4 vgam = *(const float4*)(vg    + half * 4);
    float4 vbet = *(const float4*)(vbeta + half * 4);

    // ---------- compute ----------------------------------------------------
    float4 kn = ffn_compute(fsr, fdr, ku, kv, kw2, kb1, kb2, kgam, kbet);
    float lp = dot4(kn, q4);
    lp += __shfl_xor(lp, 1);            // full DH=8 dot

    float4 vn = ffn_compute(fsr, fdr, vu, vv, vw2, vb1, vb2, vgam, vbet);

    if (lane < 2)
        *(float4*)(v_out + eh * 8 + half * 4) = vn;
    if (lane == 0) {
        float exv = expf(lp);           // no max-subtraction: identical softmax
        ex_out[eh] = exv;
        atomicAdd(s_den + dn * NH + hh, exv);
    }
}

__global__ void zero_kernel(float* __restrict__ p, int n) {
    int i = blockIdx.x * blockDim.x + threadIdx.x;
    if (i < n) p[i] = 0.0f;
}

__global__ void attn_agg_kernel(
    const int* __restrict__ dst, const float* __restrict__ ex,
    const float* __restrict__ s_den, const float* __restrict__ v,
    float* __restrict__ agg, float* __restrict__ attn_out)
{
    int tid = blockIdx.x * blockDim.x + threadIdx.x;
    if (tid >= NE * NH * DHD) return;
    int eh = tid >> 3;
    int dd = tid & 7;
    int e  = eh >> 2;
    int h  = eh & 3;
    int dn = dst[e];
    float a = ex[eh] / s_den[dn * NH + h];
    if (dd == 0) attn_out[eh] = a;
    atomicAdd(agg + (dn * NH + h) * DHD + dd, v[tid] * a);
}

__global__ void out_ln_kernel(
    const float* __restrict__ agg, const float* __restrict__ g,
    const float* __restrict__ b, float* __restrict__ out)
{
    int tid = blockIdx.x * blockDim.x + threadIdx.x;
    if (tid >= NN * NH) return;
    float4 a0 = *(const float4*)(agg + tid * 8);
    float4 a1 = *(const float4*)(agg + tid * 8 + 4);
    float s1 = a0.x + a0.y + a0.z + a0.w + a1.x + a1.y + a1.z + a1.w;
    float s2 = a0.x * a0.x + a0.y * a0.y + a0.z * a0.z + a0.w * a0.w
             + a1.x * a1.x + a1.y * a1.y + a1.z * a1.z + a1.w * a1.w;
    float mean = s1 * 0.125f;
    float var  = s2 * 0.125f - mean * mean;
    float rs   = rsqrtf(var + EPSC);
    float4 g0 = *(const float4*)(g);
    float4 g1 = *(const float4*)(g + 4);
    float4 b0 = *(const float4*)(b);
    float4 b1 = *(const float4*)(b + 4);
    float4 r0, r1;
    r0.x = (a0.x - mean) * rs * g0.x + b0.x;
    r0.y = (a0.y - mean) * rs * g0.y + b0.y;
    r0.z = (a0.z - mean) * rs * g0.z + b0.z;
    r0.w = (a0.w - mean) * rs * g0.w + b0.w;
    r1.x = (a1.x - mean) * rs * g1.x + b1.x;
    r1.y = (a1.y - mean) * rs * g1.y + b1.y;
    r1.z = (a1.z - mean) * rs * g1.z + b1.z;
    r1.w = (a1.w - mean) * rs * g1.w + b1.w;
    *(float4*)(out + tid * 8)     = r0;
    *(float4*)(out + tid * 8 + 4) = r1;
}

extern "C" void kernel_launch(void* const* d_in, const int* in_sizes, int n_in,
                              void* d_out, int out_size, void* d_ws, size_t ws_size,
                              hipStream_t stream) {
    const float* feat  = (const float*)d_in[0];
    const float* query = (const float*)d_in[1];
    const float* skw   = (const float*)d_in[2];
    const float* dkw   = (const float*)d_in[3];
    const float* skb   = (const float*)d_in[4];
    const float* dkb   = (const float*)d_in[5];
    const float* ekw   = (const float*)d_in[6];
    const float* ekb   = (const float*)d_in[7];
    const float* svw   = (const float*)d_in[8];
    const float* dvw   = (const float*)d_in[9];
    const float* svb   = (const float*)d_in[10];
    const float* dvb   = (const float*)d_in[11];
    const float* evw   = (const float*)d_in[12];
    const float* evb   = (const float*)d_in[13];
    const float* kg    = (const float*)d_in[14];
    const float* kbeta = (const float*)d_in[15];
    const float* vg    = (const float*)d_in[16];
    const float* vbeta = (const float*)d_in[17];
    const float* og    = (const float*)d_in[18];
    const float* obeta = (const float*)d_in[19];
    const int*   src   = (const int*)d_in[20];
    const int*   dst   = (const int*)d_in[21];
    // d_in[22] = i, always 0 (L=1)

    float* ws    = (float*)d_ws;
    float* s_den = ws;                 // N*H          = 10000
    float* agg   = ws + 10000;         // N*H*DH       = 80000
    float* ex    = ws + 90000;         // E*H          = 40000
    float* vbuf  = ws + 130000;        // E*H*DH       = 320000

    float* out  = (float*)d_out;       // N*EMB = 80000 floats
    float* attn = out + NN * EMBD;     // E*H   = 40000 floats
    (void)attn;

    zero_kernel<<<(90000 + 255) / 256, 256, 0, stream>>>(ws, 90000);

    edge_kernel<<<(NE * NH * 64) / 256, 256, 0, stream>>>(
        feat, query, skw, dkw, skb, dkb, ekw, ekb,
        svw, dvw, svb, dvb, evw, evb,
        kg, kbeta, vg, vbeta, src, dst,
        s_den, ex, vbuf);

    attn_agg_kernel<<<(NE * NH * DHD + 255) / 256, 256, 0, stream>>>(
        dst, ex, s_den, vbuf, agg, out + NN * EMBD);

    out_ln_kernel<<<(NN * NH + 255) / 256, 256, 0, stream>>>(
        agg, og, obeta, out);
}

// Round 4
// 148.462 us; speedup vs baseline: 1.2105x; 1.1262x over previous
//
#include <hip/hip_runtime.h>

#define NN   2500
#define NE   10000
#define EMBD 32
#define NH   4
#define DHD  8
#define FFD  32
#define EPSC 1e-5f

__device__ __forceinline__ float dot4(float4 a, float4 b) {
    return a.x * b.x + a.y * b.y + a.z * b.z + a.w * b.w;
}

// Compute one FFN path from PRE-LOADED registers.
// lane = f2*2 + half; layer-1 row f2, cols [half*16, half*16+16).
__device__ __forceinline__ float4 ffn_compute(
    const float4* fs, const float4* fd,
    const float4* u, const float4* v,
    float4 w2, float b1, float4 b2,
    float4 g4, float4 bt4)
{
    float p = dot4(u[0], fs[0]) + dot4(u[1], fs[1])
            + dot4(u[2], fs[2]) + dot4(u[3], fs[3])
            + dot4(v[0], fd[0]) + dot4(v[1], fd[1])
            + dot4(v[2], fd[2]) + dot4(v[3], fd[3]);
    p += __shfl_xor(p, 1);                     // complete EMB=32 dot
    float hv = fmaxf(p + b1, 0.0f);

    float4 o;
    o.x = w2.x * hv; o.y = w2.y * hv; o.z = w2.z * hv; o.w = w2.w * hv;
    #pragma unroll
    for (int m = 2; m <= 32; m <<= 1) {        // reduce over 32 f-rows
        o.x += __shfl_xor(o.x, m);
        o.y += __shfl_xor(o.y, m);
        o.z += __shfl_xor(o.z, m);
        o.w += __shfl_xor(o.w, m);
    }
    o.x += b2.x; o.y += b2.y; o.z += b2.z; o.w += b2.w;

    // LayerNorm over DH=8 (4 local + 4 in paired lane)
    float s1 = o.x + o.y + o.z + o.w;
    float s2 = o.x * o.x + o.y * o.y + o.z * o.z + o.w * o.w;
    s1 += __shfl_xor(s1, 1);
    s2 += __shfl_xor(s2, 1);
    float mean = s1 * 0.125f;
    float var  = s2 * 0.125f - mean * mean;
    float rs   = rsqrtf(var + EPSC);
    o.x = (o.x - mean) * rs * g4.x + bt4.x;
    o.y = (o.y - mean) * rs * g4.y + bt4.y;
    o.z = (o.z - mean) * rs * g4.z + bt4.z;
    o.w = (o.w - mean) * rs * g4.w + bt4.w;
    return o;
}

// __launch_bounds__(256, 2): 2 waves/SIMD -> VGPR budget 256, 8 waves/CU.
// All ~40 independent loads per wave are issued before the scheduling
// barrier below, so each wave has ~10 KB in flight; 8 waves/CU saturate HBM.
__global__ __launch_bounds__(256, 2) void edge_kernel(
    const float* __restrict__ feat, const float* __restrict__ query,
    const float* __restrict__ skw, const float* __restrict__ dkw,
    const float* __restrict__ skb, const float* __restrict__ dkb,
    const float* __restrict__ ekw, const float* __restrict__ ekb,
    const float* __restrict__ svw, const float* __restrict__ dvw,
    const float* __restrict__ svb, const float* __restrict__ dvb,
    const float* __restrict__ evw, const float* __restrict__ evb,
    const float* __restrict__ kg, const float* __restrict__ kbeta,
    const float* __restrict__ vg, const float* __restrict__ vbeta,
    const int* __restrict__ src, const int* __restrict__ dst,
    float* __restrict__ s_den, float* __restrict__ ex_out,
    float* __restrict__ v_out)
{
    int gid = blockIdx.x * 256 + threadIdx.x;
    int wid = gid >> 6;                 // one wave per (edge, head)
    if (wid >= NE * NH) return;
    int lane = threadIdx.x & 63;
    int e    = wid >> 2;
    int hh   = wid & 3;
    int half = lane & 1;
    int f2   = lane >> 1;
    int sn = src[e], dn = dst[e];       // issued first: feat addrs depend on it
    size_t eh = (size_t)wid;

    // ---------- issue ALL loads (key path, feat, value path) --------------
    const float4* ku_p = (const float4*)(skw + eh * 1024 + lane * 16);
    const float4* kv_p = (const float4*)(dkw + eh * 1024 + lane * 16);
    float4 ku[4], kv[4];
    #pragma unroll
    for (int j = 0; j < 4; j++) ku[j] = ku_p[j];
    #pragma unroll
    for (int j = 0; j < 4; j++) kv[j] = kv_p[j];
    float4 kw2 = *(const float4*)(ekw + eh * 256 + f2 * DHD + half * 4);
    float  kb1 = skb[eh * 32 + f2] + dkb[eh * 32 + f2];
    float4 kb2 = *(const float4*)(ekb + eh * 8 + half * 4);
    float4 q4  = *(const float4*)(query + eh * 8 + half * 4);
    float4 kgam = *(const float4*)(kg    + half * 4);
    float4 kbet = *(const float4*)(kbeta + half * 4);

    const float4* fsp = (const float4*)(feat + sn * EMBD + half * 16);
    const float4* fdp = (const float4*)(feat + dn * EMBD + half * 16);
    float4 fsr[4], fdr[4];
    #pragma unroll
    for (int j = 0; j < 4; j++) { fsr[j] = fsp[j]; fdr[j] = fdp[j]; }

    const float4* vu_p = (const float4*)(svw + eh * 1024 + lane * 16);
    const float4* vv_p = (const float4*)(dvw + eh * 1024 + lane * 16);
    float4 vu[4], vv[4];
    #pragma unroll
    for (int j = 0; j < 4; j++) vu[j] = vu_p[j];
    #pragma unroll
    for (int j = 0; j < 4; j++) vv[j] = vv_p[j];
    float4 vw2 = *(const float4*)(evw + eh * 256 + f2 * DHD + half * 4);
    float  vb1 = svb[eh * 32 + f2] + dvb[eh * 32 + f2];
    float4 vb2 = *(const float4*)(evb + eh * 8 + half * 4);
    float4 vgam = *(const float4*)(vg    + half * 4);
    float4 vbet = *(const float4*)(vbeta + half * 4);

    // ---------- scheduling fence: no load may sink below this point -------
    // (asm may modify memory, so the compiler/machine scheduler cannot move
    //  any of the loads above across it; waitcnts still land at first use)
    asm volatile("" ::: "memory");

    float4 kn = ffn_compute(fsr, fdr, ku, kv, kw2, kb1, kb2, kgam, kbet);
    float lp = dot4(kn, q4);
    lp += __shfl_xor(lp, 1);            // full DH=8 dot

    float4 vn = ffn_compute(fsr, fdr, vu, vv, vw2, vb1, vb2, vgam, vbet);

    if (lane < 2)
        *(float4*)(v_out + eh * 8 + half * 4) = vn;
    if (lane == 0) {
        float exv = expf(lp);           // no max-subtraction: identical softmax
        ex_out[eh] = exv;
        atomicAdd(s_den + dn * NH + hh, exv);
    }
}

__global__ void zero_kernel(float* __restrict__ p, int n) {
    int i = blockIdx.x * blockDim.x + threadIdx.x;
    if (i < n) p[i] = 0.0f;
}

__global__ void attn_agg_kernel(
    const int* __restrict__ dst, const float* __restrict__ ex,
    const float* __restrict__ s_den, const float* __restrict__ v,
    float* __restrict__ agg, float* __restrict__ attn_out)
{
    int tid = blockIdx.x * blockDim.x + threadIdx.x;
    if (tid >= NE * NH * DHD) return;
    int eh = tid >> 3;
    int dd = tid & 7;
    int e  = eh >> 2;
    int h  = eh & 3;
    int dn = dst[e];
    float a = ex[eh] / s_den[dn * NH + h];
    if (dd == 0) attn_out[eh] = a;
    atomicAdd(agg + (dn * NH + h) * DHD + dd, v[tid] * a);
}

__global__ void out_ln_kernel(
    const float* __restrict__ agg, const float* __restrict__ g,
    const float* __restrict__ b, float* __restrict__ out)
{
    int tid = blockIdx.x * blockDim.x + threadIdx.x;
    if (tid >= NN * NH) return;
    float4 a0 = *(const float4*)(agg + tid * 8);
    float4 a1 = *(const float4*)(agg + tid * 8 + 4);
    float s1 = a0.x + a0.y + a0.z + a0.w + a1.x + a1.y + a1.z + a1.w;
    float s2 = a0.x * a0.x + a0.y * a0.y + a0.z * a0.z + a0.w * a0.w
             + a1.x * a1.x + a1.y * a1.y + a1.z * a1.z + a1.w * a1.w;
    float mean = s1 * 0.125f;
    float var  = s2 * 0.125f - mean * mean;
    float rs   = rsqrtf(var + EPSC);
    float4 g0 = *(const float4*)(g);
    float4 g1 = *(const float4*)(g + 4);
    float4 b0 = *(const float4*)(b);
    float4 b1 = *(const float4*)(b + 4);
    float4 r0, r1;
    r0.x = (a0.x - mean) * rs * g0.x + b0.x;
    r0.y = (a0.y - mean) * rs * g0.y + b0.y;
    r0.z = (a0.z - mean) * rs * g0.z + b0.z;
    r0.w = (a0.w - mean) * rs * g0.w + b0.w;
    r1.x = (a1.x - mean) * rs * g1.x + b1.x;
    r1.y = (a1.y - mean) * rs * g1.y + b1.y;
    r1.z = (a1.z - mean) * rs * g1.z + b1.z;
    r1.w = (a1.w - mean) * rs * g1.w + b1.w;
    *(float4*)(out + tid * 8)     = r0;
    *(float4*)(out + tid * 8 + 4) = r1;
}

extern "C" void kernel_launch(void* const* d_in, const int* in_sizes, int n_in,
                              void* d_out, int out_size, void* d_ws, size_t ws_size,
                              hipStream_t stream) {
    const float* feat  = (const float*)d_in[0];
    const float* query = (const float*)d_in[1];
    const float* skw   = (const float*)d_in[2];
    const float* dkw   = (const float*)d_in[3];
    const float* skb   = (const float*)d_in[4];
    const float* dkb   = (const float*)d_in[5];
    const float* ekw   = (const float*)d_in[6];
    const float* ekb   = (const float*)d_in[7];
    const float* svw   = (const float*)d_in[8];
    const float* dvw   = (const float*)d_in[9];
    const float* svb   = (const float*)d_in[10];
    const float* dvb   = (const float*)d_in[11];
    const float* evw   = (const float*)d_in[12];
    const float* evb   = (const float*)d_in[13];
    const float* kg    = (const float*)d_in[14];
    const float* kbeta = (const float*)d_in[15];
    const float* vg    = (const float*)d_in[16];
    const float* vbeta = (const float*)d_in[17];
    const float* og    = (const float*)d_in[18];
    const float* obeta = (const float*)d_in[19];
    const int*   src   = (const int*)d_in[20];
    const int*   dst   = (const int*)d_in[21];
    // d_in[22] = i, always 0 (L=1)

    float* ws    = (float*)d_ws;
    float* s_den = ws;                 // N*H          = 10000
    float* agg   = ws + 10000;         // N*H*DH       = 80000
    float* ex    = ws + 90000;         // E*H          = 40000
    float* vbuf  = ws + 130000;        // E*H*DH       = 320000

    float* out  = (float*)d_out;       // N*EMB = 80000 floats

    zero_kernel<<<(90000 + 255) / 256, 256, 0, stream>>>(ws, 90000);

    edge_kernel<<<(NE * NH * 64) / 256, 256, 0, stream>>>(
        feat, query, skw, dkw, skb, dkb, ekw, ekb,
        svw, dvw, svb, dvb, evw, evb,
        kg, kbeta, vg, vbeta, src, dst,
        s_den, ex, vbuf);

    attn_agg_kernel<<<(NE * NH * DHD + 255) / 256, 256, 0, stream>>>(
        dst, ex, s_den, vbuf, agg, out + NN * EMBD);

    out_ln_kernel<<<(NN * NH + 255) / 256, 256, 0, stream>>>(
        agg, og, obeta, out);
}

// Round 5
// 141.195 us; speedup vs baseline: 1.2728x; 1.0515x over previous
//
#include <hip/hip_runtime.h>

#define NN   2500
#define NE   10000
#define EMBD 32
#define NH   4
#define DHD  8
#define FFD  32
#define EPSC 1e-5f

// Native clang vector: direct VGPR-tuple asm operand (HIP float4 is a struct
// -> "indirect register input" error). Supports .x/.y/.z/.w swizzles.
typedef float vf4 __attribute__((ext_vector_type(4)));

__device__ __forceinline__ float dot4v(vf4 a, vf4 b) {
    return a.x * b.x + a.y * b.y + a.z * b.z + a.w * b.w;
}

// Compute one FFN path from PRE-LOADED registers.
// lane = f2*2 + half; layer-1 row f2, cols [half*16, half*16+16).
__device__ __forceinline__ vf4 ffn_compute(
    const vf4* fs, const vf4* fd,
    const vf4* u, const vf4* v,
    vf4 w2, float b1, vf4 b2,
    vf4 g4, vf4 bt4)
{
    float p = dot4v(u[0], fs[0]) + dot4v(u[1], fs[1])
            + dot4v(u[2], fs[2]) + dot4v(u[3], fs[3])
            + dot4v(v[0], fd[0]) + dot4v(v[1], fd[1])
            + dot4v(v[2], fd[2]) + dot4v(v[3], fd[3]);
    p += __shfl_xor(p, 1);                     // complete EMB=32 dot
    float hv = fmaxf(p + b1, 0.0f);

    vf4 o = w2 * hv;
    #pragma unroll
    for (int m = 2; m <= 32; m <<= 1) {        // reduce over 32 f-rows
        o.x += __shfl_xor(o.x, m);
        o.y += __shfl_xor(o.y, m);
        o.z += __shfl_xor(o.z, m);
        o.w += __shfl_xor(o.w, m);
    }
    o += b2;

    // LayerNorm over DH=8 (4 local + 4 in paired lane)
    float s1 = o.x + o.y + o.z + o.w;
    float s2 = o.x * o.x + o.y * o.y + o.z * o.z + o.w * o.w;
    s1 += __shfl_xor(s1, 1);
    s2 += __shfl_xor(s2, 1);
    float mean = s1 * 0.125f;
    float var  = s2 * 0.125f - mean * mean;
    float rs   = rsqrtf(var + EPSC);
    return (o - mean) * rs * g4 + bt4;
}

// __launch_bounds__(256, 2): VGPR budget 256 (2 waves/SIMD, 8 waves/CU).
// All ~37 loads per wave are pinned ABOVE the keep-alive asms by data
// dependence (a load cannot sink past a reader of its result); the
// sched_barriers stop the machine scheduler from redistributing them.
// 8 waves/CU x ~18.5KB in flight each saturates HBM.
__global__ __launch_bounds__(256, 2) void edge_kernel(
    const float* __restrict__ feat, const float* __restrict__ query,
    const float* __restrict__ skw, const float* __restrict__ dkw,
    const float* __restrict__ skb, const float* __restrict__ dkb,
    const float* __restrict__ ekw, const float* __restrict__ ekb,
    const float* __restrict__ svw, const float* __restrict__ dvw,
    const float* __restrict__ svb, const float* __restrict__ dvb,
    const float* __restrict__ evw, const float* __restrict__ evb,
    const float* __restrict__ kg, const float* __restrict__ kbeta,
    const float* __restrict__ vg, const float* __restrict__ vbeta,
    const int* __restrict__ src, const int* __restrict__ dst,
    float* __restrict__ s_den, float* __restrict__ ex_out,
    float* __restrict__ v_out)
{
    int gid = blockIdx.x * 256 + threadIdx.x;
    int wid = gid >> 6;                 // one wave per (edge, head)
    if (wid >= NE * NH) return;
    int lane = threadIdx.x & 63;
    int e    = wid >> 2;
    int hh   = wid & 3;
    int half = lane & 1;
    int f2   = lane >> 1;
    int sn = src[e], dn = dst[e];       // first: feat addresses depend on it
    size_t eh = (size_t)wid;

    // ---------- issue ALL loads (key path, feat, value path) --------------
    const vf4* ku_p = (const vf4*)(skw + eh * 1024 + lane * 16);
    const vf4* kv_p = (const vf4*)(dkw + eh * 1024 + lane * 16);
    vf4 ku[4], kv[4];
    #pragma unroll
    for (int j = 0; j < 4; j++) ku[j] = ku_p[j];
    #pragma unroll
    for (int j = 0; j < 4; j++) kv[j] = kv_p[j];
    vf4 kw2 = *(const vf4*)(ekw + eh * 256 + f2 * DHD + half * 4);
    float kb1 = skb[eh * 32 + f2] + dkb[eh * 32 + f2];
    vf4 kb2 = *(const vf4*)(ekb + eh * 8 + half * 4);
    vf4 q4  = *(const vf4*)(query + eh * 8 + half * 4);
    vf4 kgam = *(const vf4*)(kg    + half * 4);
    vf4 kbet = *(const vf4*)(kbeta + half * 4);

    const vf4* fsp = (const vf4*)(feat + sn * EMBD + half * 16);
    const vf4* fdp = (const vf4*)(feat + dn * EMBD + half * 16);
    vf4 fsr[4], fdr[4];
    #pragma unroll
    for (int j = 0; j < 4; j++) { fsr[j] = fsp[j]; fdr[j] = fdp[j]; }

    const vf4* vu_p = (const vf4*)(svw + eh * 1024 + lane * 16);
    const vf4* vv_p = (const vf4*)(dvw + eh * 1024 + lane * 16);
    vf4 vu[4], vv[4];
    #pragma unroll
    for (int j = 0; j < 4; j++) vu[j] = vu_p[j];
    #pragma unroll
    for (int j = 0; j < 4; j++) vv[j] = vv_p[j];
    vf4 vw2 = *(const vf4*)(evw + eh * 256 + f2 * DHD + half * 4);
    float vb1 = svb[eh * 32 + f2] + dvb[eh * 32 + f2];
    vf4 vb2 = *(const vf4*)(evb + eh * 8 + half * 4);
    vf4 vgam = *(const vf4*)(vg    + half * 4);
    vf4 vbet = *(const vf4*)(vbeta + half * 4);

    // ---------- fence: every loaded value consumed here --------------------
    __builtin_amdgcn_sched_barrier(0);
    asm volatile("" ::
        "v"(ku[0]), "v"(ku[1]), "v"(ku[2]), "v"(ku[3]),
        "v"(kv[0]), "v"(kv[1]), "v"(kv[2]), "v"(kv[3]),
        "v"(kw2), "v"(kb2), "v"(q4), "v"(kgam), "v"(kbet), "v"(kb1));
    asm volatile("" ::
        "v"(fsr[0]), "v"(fsr[1]), "v"(fsr[2]), "v"(fsr[3]),
        "v"(fdr[0]), "v"(fdr[1]), "v"(fdr[2]), "v"(fdr[3]));
    asm volatile("" ::
        "v"(vu[0]), "v"(vu[1]), "v"(vu[2]), "v"(vu[3]),
        "v"(vv[0]), "v"(vv[1]), "v"(vv[2]), "v"(vv[3]),
        "v"(vw2), "v"(vb2), "v"(vgam), "v"(vbet), "v"(vb1));
    __builtin_amdgcn_sched_barrier(0);

    // ---------- compute ----------------------------------------------------
    vf4 kn = ffn_compute(fsr, fdr, ku, kv, kw2, kb1, kb2, kgam, kbet);
    float lp = dot4v(kn, q4);
    lp += __shfl_xor(lp, 1);            // full DH=8 dot

    vf4 vn = ffn_compute(fsr, fdr, vu, vv, vw2, vb1, vb2, vgam, vbet);

    if (lane < 2)
        *(vf4*)(v_out + eh * 8 + half * 4) = vn;
    if (lane == 0) {
        float exv = expf(lp);           // no max-subtraction: identical softmax
        ex_out[eh] = exv;
        atomicAdd(s_den + dn * NH + hh, exv);
    }
}

__global__ void zero_kernel(float* __restrict__ p, int n) {
    int i = blockIdx.x * blockDim.x + threadIdx.x;
    if (i < n) p[i] = 0.0f;
}

__global__ void attn_agg_kernel(
    const int* __restrict__ dst, const float* __restrict__ ex,
    const float* __restrict__ s_den, const float* __restrict__ v,
    float* __restrict__ agg, float* __restrict__ attn_out)
{
    int tid = blockIdx.x * blockDim.x + threadIdx.x;
    if (tid >= NE * NH * DHD) return;
    int eh = tid >> 3;
    int dd = tid & 7;
    int e  = eh >> 2;
    int h  = eh & 3;
    int dn = dst[e];
    float a = ex[eh] / s_den[dn * NH + h];
    if (dd == 0) attn_out[eh] = a;
    atomicAdd(agg + (dn * NH + h) * DHD + dd, v[tid] * a);
}

__global__ void out_ln_kernel(
    const float* __restrict__ agg, const float* __restrict__ g,
    const float* __restrict__ b, float* __restrict__ out)
{
    int tid = blockIdx.x * blockDim.x + threadIdx.x;
    if (tid >= NN * NH) return;
    vf4 a0 = *(const vf4*)(agg + tid * 8);
    vf4 a1 = *(const vf4*)(agg + tid * 8 + 4);
    float s1 = a0.x + a0.y + a0.z + a0.w + a1.x + a1.y + a1.z + a1.w;
    float s2 = a0.x * a0.x + a0.y * a0.y + a0.z * a0.z + a0.w * a0.w
             + a1.x * a1.x + a1.y * a1.y + a1.z * a1.z + a1.w * a1.w;
    float mean = s1 * 0.125f;
    float var  = s2 * 0.125f - mean * mean;
    float rs   = rsqrtf(var + EPSC);
    vf4 g0 = *(const vf4*)(g);
    vf4 g1 = *(const vf4*)(g + 4);
    vf4 b0 = *(const vf4*)(b);
    vf4 b1 = *(const vf4*)(b + 4);
    *(vf4*)(out + tid * 8)     = (a0 - mean) * rs * g0 + b0;
    *(vf4*)(out + tid * 8 + 4) = (a1 - mean) * rs * g1 + b1;
}

extern "C" void kernel_launch(void* const* d_in, const int* in_sizes, int n_in,
                              void* d_out, int out_size, void* d_ws, size_t ws_size,
                              hipStream_t stream) {
    const float* feat  = (const float*)d_in[0];
    const float* query = (const float*)d_in[1];
    const float* skw   = (const float*)d_in[2];
    const float* dkw   = (const float*)d_in[3];
    const float* skb   = (const float*)d_in[4];
    const float* dkb   = (const float*)d_in[5];
    const float* ekw   = (const float*)d_in[6];
    const float* ekb   = (const float*)d_in[7];
    const float* svw   = (const float*)d_in[8];
    const float* dvw   = (const float*)d_in[9];
    const float* svb   = (const float*)d_in[10];
    const float* dvb   = (const float*)d_in[11];
    const float* evw   = (const float*)d_in[12];
    const float* evb   = (const float*)d_in[13];
    const float* kg    = (const float*)d_in[14];
    const float* kbeta = (const float*)d_in[15];
    const float* vg    = (const float*)d_in[16];
    const float* vbeta = (const float*)d_in[17];
    const float* og    = (const float*)d_in[18];
    const float* obeta = (const float*)d_in[19];
    const int*   src   = (const int*)d_in[20];
    const int*   dst   = (const int*)d_in[21];
    // d_in[22] = i, always 0 (L=1)

    float* ws    = (float*)d_ws;
    float* s_den = ws;                 // N*H          = 10000
    float* agg   = ws + 10000;         // N*H*DH       = 80000
    float* ex    = ws + 90000;         // E*H          = 40000
    float* vbuf  = ws + 130000;        // E*H*DH       = 320000

    float* out  = (float*)d_out;       // N*EMB = 80000 floats

    zero_kernel<<<(90000 + 255) / 256, 256, 0, stream>>>(ws, 90000);

    edge_kernel<<<(NE * NH * 64) / 256, 256, 0, stream>>>(
        feat, query, skw, dkw, skb, dkb, ekw, ekb,
        svw, dvw, svb, dvb, evw, evb,
        kg, kbeta, vg, vbeta, src, dst,
        s_den, ex, vbuf);

    attn_agg_kernel<<<(NE * NH * DHD + 255) / 256, 256, 0, stream>>>(
        dst, ex, s_den, vbuf, agg, out + NN * EMBD);

    out_ln_kernel<<<(NN * NH + 255) / 256, 256, 0, stream>>>(
        agg, og, obeta, out);
}